// Round 9
// baseline (424.753 us; speedup 1.0000x reference)
//
#include <hip/hip_runtime.h>
#include <stdint.h>

typedef unsigned short ushort_t;
typedef __attribute__((ext_vector_type(8))) __bf16 bf16x8;
typedef __attribute__((ext_vector_type(4))) float floatx4;

__device__ __forceinline__ ushort_t f2bf(float f) {
    uint32_t u = __builtin_bit_cast(uint32_t, f);
    u += 0x7fffu + ((u >> 16) & 1u);
    return (ushort_t)(u >> 16);
}

// async 16B global->LDS (deposit at ldsbase + lane*16; ldsbase wave-uniform)
typedef __attribute__((address_space(1))) const void glb_void;
typedef __attribute__((address_space(3))) void lds_void;
__device__ __forceinline__ void gld16(const void* g, void* l) {
    __builtin_amdgcn_global_load_lds((glb_void*)g, (lds_void*)l, 16, 0, 0);
}

// Q pre-scale: dh^-0.5 * log2(e) so attention softmax runs in exp2 domain.
#define QSCALE 0.18033688011112042f

// ---------------- cast: fp32 -> bf16 ----------------
__global__ void cast_kernel(const float* __restrict__ x,
                            const float* __restrict__ Wq, const float* __restrict__ Wk,
                            const float* __restrict__ Wv, const float* __restrict__ Wp,
                            ushort_t* __restrict__ xb, ushort_t* __restrict__ Wqkvb,
                            ushort_t* __restrict__ Wpb)
{
    const int64_t NX = 4194304, NW = 1048576;
    int64_t i4 = ((int64_t)blockIdx.x * blockDim.x + threadIdx.x) * 4;
    const float* src; ushort_t* dst; int64_t off;
    if (i4 < NX)            { src = x;  dst = xb;          off = i4; }
    else if (i4 < NX+NW)    { src = Wq; dst = Wqkvb;       off = i4 - NX; }
    else if (i4 < NX+2*NW)  { src = Wk; dst = Wqkvb + NW;  off = i4 - NX - NW; }
    else if (i4 < NX+3*NW)  { src = Wv; dst = Wqkvb + 2*NW;off = i4 - NX - 2*NW; }
    else                    { src = Wp; dst = Wpb;         off = i4 - NX - 3*NW; }
    float4 v = *(const float4*)(src + off);
    ushort4 o;
    o.x = f2bf(v.x); o.y = f2bf(v.y); o.z = f2bf(v.z); o.w = f2bf(v.w);
    *(ushort4*)(dst + off) = o;
}

// ---------------- bf16 GEMM: D = A @ B^T  (global_load_lds staging) ----------------
// MODE 0 (BN_=128): scatter Q,K -> [bh][s][d] (Q pre-scaled), V -> [bh][d][s]
// MODE 1: fp32 out = D + bias
#define BM 128
#define BK 32

template<int BN_, int MODE>
__global__ __launch_bounds__(256, 3)
void gemm_bt(const ushort_t* __restrict__ A, const ushort_t* __restrict__ Bmat,
             int M, int N, int K,
             ushort_t* __restrict__ qb, ushort_t* __restrict__ kb, ushort_t* __restrict__ vtb,
             float* __restrict__ outf, const float* __restrict__ bias)
{
    constexpr int NB_B = BN_ * BK / 512;
    constexpr int NT   = BN_ / 32;
    constexpr int PER_W = (8 + NB_B) / 4;
    __shared__ ushort_t As[BM * BK];
    __shared__ ushort_t Bs[BN_ * BK];
    const int tid  = threadIdx.x;
    const int lane = tid & 63;
    const int wave = tid >> 6;
    const int m0 = blockIdx.x * BM;
    const int n0 = blockIdx.y * BN_;
    const int wrow = (wave >> 1) * 64;
    const int wcol = (wave & 1) * (BN_ / 2);
    const int q_ = lane >> 4;
    const int ml = lane & 15;

    floatx4 acc[4][NT];
    for (int i = 0; i < 4; i++) for (int j = 0; j < NT; j++) acc[i][j] = floatx4{0.f,0.f,0.f,0.f};

    const int row_l = lane >> 2;
    const int col_l = (lane & 3) * 8;
    const ushort_t* gptr[PER_W]; ushort_t* lptr[PER_W];
    for (int i = 0; i < PER_W; i++) {
        int id = wave * PER_W + i;
        if (id < 8) {
            gptr[i] = A + (int64_t)(m0 + id*16 + row_l) * K + col_l;
            lptr[i] = As + id * 512;
        } else {
            int j = id - 8;
            gptr[i] = Bmat + (int64_t)(n0 + j*16 + row_l) * K + col_l;
            lptr[i] = Bs + j * 512;
        }
    }

    for (int k0 = 0; k0 < K; k0 += BK) {
        __syncthreads();
        for (int i = 0; i < PER_W; i++) gld16(gptr[i] + k0, lptr[i]);
        __syncthreads();
        bf16x8 af[4], bf[NT];
        for (int mt = 0; mt < 4; mt++)
            af[mt] = *(const bf16x8*)(As + (wrow + mt*16 + ml) * BK + q_*8);
        for (int nt = 0; nt < NT; nt++)
            bf[nt] = *(const bf16x8*)(Bs + (wcol + nt*16 + ml) * BK + q_*8);
        for (int mt = 0; mt < 4; mt++)
            for (int nt = 0; nt < NT; nt++)
                acc[mt][nt] = __builtin_amdgcn_mfma_f32_16x16x32_bf16(af[mt], bf[nt], acc[mt][nt], 0, 0, 0);
    }

    if constexpr (MODE == 0) {
        for (int mt = 0; mt < 4; mt++) for (int nt = 0; nt < NT; nt++) {
            floatx4 v = acc[mt][nt];
            int col = n0 + wcol + nt*16 + ml;
            int which = col >> 10;
            int nn = col & 1023;
            int h = nn >> 6, d = nn & 63;
            if (which < 2) {
                ushort_t* dst = (which == 0) ? qb : kb;
                float sc = (which == 0) ? QSCALE : 1.0f;
                for (int r = 0; r < 4; r++) {
                    int rowg = m0 + wrow + mt*16 + q_*4 + r;
                    int b = rowg >> 11, s = rowg & 2047;
                    dst[(((int64_t)(b*16 + h) * 2048 + s) << 6) + d] = f2bf(v[r] * sc);
                }
            } else {
                int rowg0 = m0 + wrow + mt*16 + q_*4;
                int b = rowg0 >> 11, sbase = rowg0 & 2047;
                ushort4 o;
                o.x = f2bf(v[0]); o.y = f2bf(v[1]); o.z = f2bf(v[2]); o.w = f2bf(v[3]);
                *(ushort4*)(vtb + (((int64_t)(b*16 + h) * 64 + d) << 11) + sbase) = o;
            }
        }
    } else {
        for (int mt = 0; mt < 4; mt++) for (int nt = 0; nt < NT; nt++) {
            floatx4 v = acc[mt][nt];
            int col = n0 + wcol + nt*16 + ml;
            float bv = bias[col];
            for (int r = 0; r < 4; r++) {
                int rowg = m0 + wrow + mt*16 + q_*4 + r;
                outf[(int64_t)rowg * N + col] = v[r] + bv;
            }
        }
    }
}

// ---------------- view-parallel attention, operand-swapped MFMA ----------------
// 4480 UNIFORM blocks: (bh, 64-row q-tile, one 256-key view). Unnormalized O and
// partial l accumulated via fp32 atomicAdd; finalize kernel divides.
// Inner loop identical to R8 (S^T = K·Q^T, O^T = V^T·P^T, key-permuted K staging).
__global__ __launch_bounds__(128, 2)
void attn_kernel(const ushort_t* __restrict__ Q, const ushort_t* __restrict__ Kb,
                 const ushort_t* __restrict__ Vt,
                 float* __restrict__ accO, float* __restrict__ accL)
{
    __shared__ ushort_t Kl[8192];   // 16KB: 16 cells of 1KB, key-permuted rows
    __shared__ ushort_t Vl[8192];   // 16KB: 16 cells of 1KB, lane-linear

    int bi = blockIdx.x;            // 4480 blocks
    int bh  = (bi & 7) + 8 * ((bi >> 3) & 3);   // XCD-pinned
    int slot = bi >> 5;             // 0..139
    int qt = slot & 3;
    int vs = slot >> 2;             // 0..34
    int qv, view;
    if      (vs < 8)  { qv = 7; view = vs; }
    else if (vs < 15) { qv = 6; view = vs - 8; }
    else if (vs < 21) { qv = 5; view = vs - 15; }
    else if (vs < 26) { qv = 4; view = vs - 21; }
    else if (vs < 30) { qv = 3; view = vs - 26; }
    else if (vs < 33) { qv = 2; view = vs - 30; }
    else if (vs == 33){ qv = 1; view = 0; }
    else              { qv = 0; view = 1; }
    int b = bh >> 4, h = bh & 15;
    int tid = threadIdx.x;
    int wave = tid >> 6, lane = tid & 63;
    int q_ = lane >> 4, ml = lane & 15;
    int s0 = qv*256 + qt*64 + wave*32;
    int kb0 = view * 256;

    const ushort_t* Kbh = Kb + ((int64_t)bh << 17);
    const ushort_t* Vbh = Vt + ((int64_t)bh << 17);

    // Q as B-operand: lane holds Q[s0+qf*16+ml][32*hh + 8*q_ .. +7]
    bf16x8 bq[2][2];
    for (int qf = 0; qf < 2; qf++)
        for (int hh = 0; hh < 2; hh++)
            bq[qf][hh] = *(const bf16x8*)(Q + (((int64_t)bh*2048 + s0 + qf*16 + ml) << 6)
                                          + hh*32 + q_*8);

    floatx4 o_acc[2][4];
    for (int qf = 0; qf < 2; qf++) for (int i = 0; i < 4; i++) o_acc[qf][i] = floatx4{0.f,0.f,0.f,0.f};
    float lsum[2] = {0.f, 0.f};

    // staging lane decomposition (per wave)
    int m_ = lane & 15, q5 = lane >> 4;
    int kperm = (m_ >> 2)*8 + (m_ & 3);       // key-permuted row within 32-key window

    for (int ck = 0; ck < 2; ck++) {
        int koff = kb0 + ck * 128;

        __syncthreads();   // prior chunk's LDS reads complete
        if (wave == 0) {
            #pragma unroll
            for (int id = 0; id < 16; id++) {
                int w = id >> 2, t = (id >> 1) & 1, hh = id & 1;
                const ushort_t* g = Kbh
                    + (((int64_t)(koff + w*32 + t*4 + kperm)) << 6) + hh*32 + q5*8;
                gld16(g, Kl + id*512);
            }
        } else {
            #pragma unroll
            for (int id = 0; id < 16; id++) {
                int w = id >> 2, dt = id & 3;
                const ushort_t* g = Vbh
                    + ((int64_t)(dt*16 + m_) << 11) + koff + w*32 + q5*8;
                gld16(g, Vl + id*512);
            }
        }
        __syncthreads();   // loads landed

        #pragma unroll
        for (int w = 0; w < 4; w++) {
            floatx4 st[2][2];   // [t][qf]
            #pragma unroll
            for (int t = 0; t < 2; t++) {
                bf16x8 k0 = *(const bf16x8*)(Kl + (w*4 + t*2 + 0)*512 + lane*8);
                bf16x8 k1 = *(const bf16x8*)(Kl + (w*4 + t*2 + 1)*512 + lane*8);
                #pragma unroll
                for (int qf = 0; qf < 2; qf++) {
                    floatx4 cz = floatx4{0.f,0.f,0.f,0.f};
                    cz = __builtin_amdgcn_mfma_f32_16x16x32_bf16(k0, bq[qf][0], cz, 0, 0, 0);
                    cz = __builtin_amdgcn_mfma_f32_16x16x32_bf16(k1, bq[qf][1], cz, 0, 0, 0);
                    st[t][qf] = cz;
                }
            }
            bf16x8 pb[2];
            #pragma unroll
            for (int qf = 0; qf < 2; qf++) {
                union { ushort_t u[8]; bf16x8 v; } pu;
                #pragma unroll
                for (int t = 0; t < 2; t++)
                    #pragma unroll
                    for (int r = 0; r < 4; r++) {
                        float p = __builtin_amdgcn_exp2f(st[t][qf][r]);
                        lsum[qf] += p;
                        pu.u[t*4 + r] = f2bf(p);
                    }
                pb[qf] = pu.v;
            }
            #pragma unroll
            for (int dt = 0; dt < 4; dt++) {
                bf16x8 vf = *(const bf16x8*)(Vl + (w*4 + dt)*512 + lane*8);
                #pragma unroll
                for (int qf = 0; qf < 2; qf++)
                    o_acc[qf][dt] = __builtin_amdgcn_mfma_f32_16x16x32_bf16(vf, pb[qf], o_acc[qf][dt], 0, 0, 0);
            }
        }
    }

    // epilogue: accumulate unnormalized O^T and partial l (device-scope atomics)
    for (int qf = 0; qf < 2; qf++) {
        int sr = s0 + qf*16 + ml;
        float* rowp = accO + (((int64_t)b*2048 + sr) << 10) + h*64;
        for (int dt = 0; dt < 4; dt++)
            for (int r = 0; r < 4; r++)
                atomicAdd(rowp + dt*16 + q_*4 + r, o_acc[qf][dt][r]);
        atomicAdd(accL + bh*2048 + sr, lsum[qf]);
    }
}

// ---------------- finalize: attno = accO / accL (bf16) ----------------
__global__ void attn_finalize(const float* __restrict__ accO, const float* __restrict__ accL,
                              ushort_t* __restrict__ attno)
{
    int t = blockIdx.x * 256 + threadIdx.x;      // 1,048,576 threads
    int64_t e = (int64_t)t * 4;
    int c = (int)(e & 1023);
    int s = (int)((e >> 10) & 2047);
    int b = (int)(e >> 21);
    float inv = 1.0f / accL[(b*16 + (c >> 6))*2048 + s];
    float4 v = *(const float4*)(accO + e);
    ushort4 o;
    o.x = f2bf(v.x * inv); o.y = f2bf(v.y * inv);
    o.z = f2bf(v.z * inv); o.w = f2bf(v.w * inv);
    *(ushort4*)(attno + e) = o;
}

extern "C" void kernel_launch(void* const* d_in, const int* in_sizes, int n_in,
                              void* d_out, int out_size, void* d_ws, size_t ws_size,
                              hipStream_t stream) {
    const float* x  = (const float*)d_in[0];
    const float* Wq = (const float*)d_in[1];
    const float* Wk = (const float*)d_in[2];
    const float* Wv = (const float*)d_in[3];
    const float* Wp = (const float*)d_in[4];
    const float* bp = (const float*)d_in[5];
    float* out = (float*)d_out;

    char* ws = (char*)d_ws;
    ushort_t* xb    = (ushort_t*)(ws);                       // 8MB (reused as attno)
    ushort_t* Wqkvb = (ushort_t*)(ws + ((size_t)8  << 20));  // 6MB
    ushort_t* Wpb   = (ushort_t*)(ws + ((size_t)14 << 20));  // 2MB
    ushort_t* qb    = (ushort_t*)(ws + ((size_t)16 << 20));  // 8MB
    ushort_t* kbuf  = (ushort_t*)(ws + ((size_t)24 << 20));  // 8MB
    float*    accL  = (float*)   (ws + ((size_t)32 << 20));  // 256KB
    ushort_t* vtb   = (ushort_t*)(ws + ((size_t)40 << 20));  // 8MB
    float*    accO  = (float*)   (ws + ((size_t)48 << 20));  // 16MB -> 64MB total
    ushort_t* attno = xb;

    cast_kernel<<<8192, 256, 0, stream>>>(x, Wq, Wk, Wv, Wp, xb, Wqkvb, Wpb);

    hipMemsetAsync(accO, 0, (size_t)16 << 20, stream);
    hipMemsetAsync(accL, 0, (size_t)256 << 10, stream);

    dim3 g0(4096 / BM, 3072 / 128);
    gemm_bt<128, 0><<<g0, 256, 0, stream>>>(xb, Wqkvb, 4096, 3072, 1024,
                                            qb, kbuf, vtb, nullptr, nullptr);

    attn_kernel<<<4480, 128, 0, stream>>>(qb, kbuf, vtb, accO, accL);

    attn_finalize<<<4096, 256, 0, stream>>>(accO, accL, attno);

    dim3 g1(4096 / BM, 1024 / 64);
    gemm_bt<64, 1><<<g1, 256, 0, stream>>>(attno, Wpb, 4096, 1024, 1024,
                                           nullptr, nullptr, nullptr, out, bp);
}